// Round 3
// baseline (114.751 us; speedup 1.0000x reference)
//
#include <hip/hip_runtime.h>
#include <math.h>

// Problem constants (fixed by the reference)
#define NN   4096      // nodes per graph
#define EE   32768     // edges per graph (unique; B tiled copies are identical)
#define NB   4         // batch
#define ACc  16
#define UCc  16
#define INC  32        // AC+UC
#define OUTC 32
#define HID  8
#define EDGEC 68

__device__ __forceinline__ float gelu_exact(float v) {
    // jax.nn.gelu(approximate=False): x * 0.5 * (1 + erf(x/sqrt(2)))
    return 0.5f * v * (1.0f + erff(v * 0.70710678118654752f));
}

// ---------------------------------------------------------------------------
// Kernel 1: per-node precompute + workspace zeroing.
// Blocks [0,256): 16 nodes each.
//   nrec[n][0:32)  = x[n]            (transposed copy, contiguous per node)
//   nrec[n][32:64) = bbx[n][o] = sum_i x[n][i]*b2[i*32+o]
//   hs[n][k] = b1[k] + pw[n]·w1[k,0:34]; hd[n][k] = pw[n]·w1[k,34:68]
// Blocks [256,388): zero agg (131072 f) + cnt (4096 f) = 33792 float4.
// ---------------------------------------------------------------------------
__global__ __launch_bounds__(256) void node_kernel(
    const float* __restrict__ a, const float* __restrict__ u,
    const float* __restrict__ gpos,
    const float* __restrict__ w1, const float* __restrict__ b1,
    const float* __restrict__ b2,
    float* __restrict__ hs, float* __restrict__ hd,
    float* __restrict__ nrec, float* __restrict__ zbase)
{
    if (blockIdx.x >= 256) {
        int idx = (blockIdx.x - 256) * 256 + threadIdx.x;   // < 33792
        ((float4*)zbase)[idx] = make_float4(0.f, 0.f, 0.f, 0.f);
        return;
    }

    __shared__ float xs[16][36];       // [node][feature], 0..33 used
    __shared__ float w1s[HID * EDGEC]; // 544
    __shared__ float b2s[INC * OUTC];  // 1024
    __shared__ float b1s[HID];

    int tid = threadIdx.x;
    int n0 = blockIdx.x * 16;

    for (int i = tid; i < HID * EDGEC; i += 256) w1s[i] = w1[i];
    for (int i = tid; i < INC * OUTC; i += 256)  b2s[i] = b2[i];
    if (tid < HID) b1s[tid] = b1[tid];

    {   // stage x: 16 consecutive nodes per load group (coalesced 64B)
        int nn = tid & 15, cb = tid >> 4;
        #pragma unroll
        for (int j = 0; j < 2; ++j) {
            int c = cb + 16 * j;
            xs[nn][c] = (c < ACc) ? a[c * NN + n0 + nn]
                                  : u[(c - ACc) * NN + n0 + nn];
        }
    }
    if (tid < 32) {
        int nn = tid >> 1, dc = tid & 1;
        xs[nn][32 + dc] = gpos[(n0 + nn) * 2 + dc];
    }
    __syncthreads();

    // ---- xt + bbx: tid -> (o = tid&31, node slot = tid>>5, 2 nodes/thread)
    {
        int o = tid & 31, ns = tid >> 5;
        #pragma unroll
        for (int j = 0; j < 2; ++j) {
            int n = ns + 8 * j;
            float acc = 0.f;
            #pragma unroll
            for (int i = 0; i < INC; ++i) acc += xs[n][i] * b2s[i * OUTC + o];
            float* np = nrec + (size_t)(n0 + n) * 64;
            np[o]      = xs[n][o];
            np[32 + o] = acc;
        }
    }

    // ---- hs/hd: tid -> (n = tid>>4, idx = tid&15), one output each ----
    {
        int idx = tid & 15, n = tid >> 4;
        int k = idx & 7;
        bool dh = (idx >= 8);
        int base = k * EDGEC + (dh ? 34 : 0);
        float acc = dh ? 0.f : b1s[k];
        #pragma unroll
        for (int c = 0; c < 34; ++c) acc += xs[n][c] * w1s[base + c];
        (dh ? hd : hs)[(n0 + n) * HID + k] = acc;
    }
}

// ---------------------------------------------------------------------------
// Kernel 2: edge-parallel message + atomic scatter, NO G tensor.
// 256 threads = 32 o  x  8 k column owners; each holds w2[:,o,k] in 32 VGPRs
// (w2[(i*32+o)*8+k] == w2[i*256+tid] -> coalesced load, once per block).
// Each block handles 32 edges serially; s,d are block-uniform -> x[s] loads
// compile to scalar broadcasts.
//   g = sum_i x[s][i]*w2r[i];  m = gelu(hs[s][k]+hd[d][k]) * g
//   reduce over k-octet (3 shfl_xor); k==0 lane adds bbx and atomics.
// ---------------------------------------------------------------------------
__global__ __launch_bounds__(256) void edge_kernel(
    const int* __restrict__ ei, const float* __restrict__ w2,
    const float* __restrict__ hs, const float* __restrict__ hd,
    const float* __restrict__ nrec,
    float* __restrict__ agg, float* __restrict__ cnt)
{
    int tid = threadIdx.x;

    float w2r[INC];
    #pragma unroll
    for (int i = 0; i < INC; ++i) w2r[i] = w2[i * 256 + tid];

    int k = tid & 7;
    int o = tid >> 3;          // 0..31

    int e0 = blockIdx.x * 32;
    #pragma unroll 2
    for (int e = e0; e < e0 + 32; ++e) {
        int s = ei[e];
        int d = ei[EE + e];

        const float4* xp = (const float4*)(nrec + (size_t)s * 64);
        float4 x0 = xp[0], x1 = xp[1], x2 = xp[2], x3 = xp[3];
        float4 x4 = xp[4], x5 = xp[5], x6 = xp[6], x7 = xp[7];

        float hk = gelu_exact(hs[s * HID + k] + hd[d * HID + k]);

        float g = 0.f;
        g += x0.x*w2r[0]  + x0.y*w2r[1]  + x0.z*w2r[2]  + x0.w*w2r[3];
        g += x1.x*w2r[4]  + x1.y*w2r[5]  + x1.z*w2r[6]  + x1.w*w2r[7];
        g += x2.x*w2r[8]  + x2.y*w2r[9]  + x2.z*w2r[10] + x2.w*w2r[11];
        g += x3.x*w2r[12] + x3.y*w2r[13] + x3.z*w2r[14] + x3.w*w2r[15];
        g += x4.x*w2r[16] + x4.y*w2r[17] + x4.z*w2r[18] + x4.w*w2r[19];
        g += x5.x*w2r[20] + x5.y*w2r[21] + x5.z*w2r[22] + x5.w*w2r[23];
        g += x6.x*w2r[24] + x6.y*w2r[25] + x6.z*w2r[26] + x6.w*w2r[27];
        g += x7.x*w2r[28] + x7.y*w2r[29] + x7.z*w2r[30] + x7.w*w2r[31];

        float m = hk * g;
        m += __shfl_xor(m, 1, 64);
        m += __shfl_xor(m, 2, 64);
        m += __shfl_xor(m, 4, 64);

        if (k == 0) {
            m += nrec[(size_t)s * 64 + 32 + o];
            atomicAdd(&agg[d * OUTC + o], m);
        }
        if (tid == 0) atomicAdd(&cnt[d], 1.0f);
    }
}

// ---------------------------------------------------------------------------
// Kernel 3: output. agg holds SUM; divide by cnt here.
//   out[b,o,n] = (b==0 ? agg[n,o]/max(cnt,1) : 0) + sum_i x[b,n,i]*root[i,o]
// ---------------------------------------------------------------------------
__global__ __launch_bounds__(256) void out_kernel(
    const float* __restrict__ a, const float* __restrict__ u,
    const float* __restrict__ root, const float* __restrict__ agg,
    const float* __restrict__ cnt, float* __restrict__ out)
{
    __shared__ float rs[INC * OUTC];
    for (int i = threadIdx.x; i < INC * OUTC; i += 256) rs[i] = root[i];
    __syncthreads();

    int b     = blockIdx.x >> 7;          // 4
    int rem   = blockIdx.x & 127;
    int oq    = rem >> 4;                 // 8 o-quads
    int chunk = rem & 15;                 // 16 n-chunks
    int n = chunk * 256 + threadIdx.x;

    float x[INC];
    #pragma unroll
    for (int c = 0; c < ACc; ++c) x[c] = a[(b * ACc + c) * NN + n];
    #pragma unroll
    for (int c = 0; c < UCc; ++c) x[ACc + c] = u[(b * UCc + c) * NN + n];

    bool first = (b == 0);
    float inv = first ? 1.0f / fmaxf(cnt[n], 1.0f) : 0.0f;

    #pragma unroll
    for (int q = 0; q < 4; ++q) {
        int o = oq * 4 + q;
        float v = first ? agg[n * OUTC + o] * inv : 0.0f;
        #pragma unroll
        for (int i = 0; i < INC; ++i) v += x[i] * rs[i * OUTC + o];
        out[(b * OUTC + o) * NN + n] = v;
    }
}

// ---------------------------------------------------------------------------
// Fallback kernels (workspace too small): R0 slow path.
// ---------------------------------------------------------------------------
__global__ __launch_bounds__(256) void edge_slow_kernel(
    const float* __restrict__ a, const float* __restrict__ u,
    const float* __restrict__ gpos, const int* __restrict__ ei,
    const float* __restrict__ w1, const float* __restrict__ b1,
    const float* __restrict__ w2, const float* __restrict__ b2,
    float* __restrict__ agg, float* __restrict__ cnt)
{
    __shared__ float w1s[HID * EDGEC];
    __shared__ float b1s[HID];
    __shared__ float w2s[INC * OUTC * HID];
    __shared__ float b2s[INC * OUTC];
    for (int i = threadIdx.x; i < HID * EDGEC; i += 256)      w1s[i] = w1[i];
    for (int i = threadIdx.x; i < INC * OUTC * HID; i += 256) w2s[i] = w2[i];
    for (int i = threadIdx.x; i < INC * OUTC; i += 256)       b2s[i] = b2[i];
    if (threadIdx.x < HID) b1s[threadIdx.x] = b1[threadIdx.x];
    __syncthreads();

    int e = blockIdx.x * 256 + threadIdx.x;
    if (e >= EE) return;
    int s = ei[e];
    int d = ei[EE + e];

    float h[HID];
    #pragma unroll
    for (int k = 0; k < HID; ++k) h[k] = b1s[k];
    float xs[INC];

    #pragma unroll
    for (int c = 0; c < ACc; ++c) {
        float v = a[c * NN + s]; xs[c] = v;
        #pragma unroll
        for (int k = 0; k < HID; ++k) h[k] += v * w1s[k * EDGEC + c];
    }
    #pragma unroll
    for (int c = 0; c < UCc; ++c) {
        float v = u[c * NN + s]; xs[ACc + c] = v;
        #pragma unroll
        for (int k = 0; k < HID; ++k) h[k] += v * w1s[k * EDGEC + ACc + c];
    }
    {
        float v0 = gpos[s * 2], v1 = gpos[s * 2 + 1];
        #pragma unroll
        for (int k = 0; k < HID; ++k)
            h[k] += v0 * w1s[k * EDGEC + 32] + v1 * w1s[k * EDGEC + 33];
    }
    #pragma unroll
    for (int c = 0; c < ACc; ++c) {
        float v = a[c * NN + d];
        #pragma unroll
        for (int k = 0; k < HID; ++k) h[k] += v * w1s[k * EDGEC + 34 + c];
    }
    #pragma unroll
    for (int c = 0; c < UCc; ++c) {
        float v = u[c * NN + d];
        #pragma unroll
        for (int k = 0; k < HID; ++k) h[k] += v * w1s[k * EDGEC + 50 + c];
    }
    {
        float v0 = gpos[d * 2], v1 = gpos[d * 2 + 1];
        #pragma unroll
        for (int k = 0; k < HID; ++k)
            h[k] += v0 * w1s[k * EDGEC + 66] + v1 * w1s[k * EDGEC + 67];
    }
    #pragma unroll
    for (int k = 0; k < HID; ++k) h[k] = gelu_exact(h[k]);

    float* aggd = agg + d * OUTC;
    for (int o = 0; o < OUTC; ++o) {
        float m = 0.0f;
        #pragma unroll 4
        for (int i = 0; i < INC; ++i) {
            int r = i * OUTC + o;
            float wv = b2s[r];
            const float* wp = &w2s[r * HID];
            #pragma unroll
            for (int k = 0; k < HID; ++k) wv += h[k] * wp[k];
            m += xs[i] * wv;
        }
        atomicAdd(aggd + o, m);
    }
    atomicAdd(cnt + d, 1.0f);
}

__global__ __launch_bounds__(64) void out_fallback_kernel(
    const float* __restrict__ a, const float* __restrict__ u,
    const float* __restrict__ root,
    const float* __restrict__ agg, const float* __restrict__ cnt,
    float* __restrict__ out)
{
    __shared__ float rs[INC * OUTC];
    for (int i = threadIdx.x; i < INC * OUTC; i += 64) rs[i] = root[i];
    __syncthreads();

    int idx = blockIdx.x * 64 + threadIdx.x;
    int b = idx >> 12;
    int n = idx & (NN - 1);

    float x[INC];
    #pragma unroll
    for (int c = 0; c < ACc; ++c) x[c] = a[(b * ACc + c) * NN + n];
    #pragma unroll
    for (int c = 0; c < UCc; ++c) x[ACc + c] = u[(b * UCc + c) * NN + n];

    bool first = (b == 0);
    float inv = 0.0f;
    if (first) inv = 1.0f / fmaxf(cnt[n], 1.0f);

    for (int o = 0; o < OUTC; ++o) {
        float v = first ? agg[n * OUTC + o] * inv : 0.0f;
        #pragma unroll
        for (int i = 0; i < INC; ++i) v += x[i] * rs[i * OUTC + o];
        out[(b * OUTC + o) * NN + n] = v;
    }
}

extern "C" void kernel_launch(void* const* d_in, const int* in_sizes, int n_in,
                              void* d_out, int out_size, void* d_ws, size_t ws_size,
                              hipStream_t stream) {
    const float* a    = (const float*)d_in[0];
    const float* u    = (const float*)d_in[1];
    const float* gpos = (const float*)d_in[2];
    const int*   ei   = (const int*)d_in[3];
    const float* w1   = (const float*)d_in[4];
    const float* b1   = (const float*)d_in[5];
    const float* w2   = (const float*)d_in[6];
    const float* b2   = (const float*)d_in[7];
    const float* root = (const float*)d_in[8];
    float* out = (float*)d_out;

    float* ws = (float*)d_ws;

    // fast-path workspace layout (floats):
    //   agg  [0,       +131072)
    //   cnt  [131072,  +4096)     (agg..cnt zeroed by node_kernel tail blocks)
    //   hs   [135168,  +32768)
    //   hd   [167936,  +32768)
    //   nrec [200704,  +262144)   (xt 32 + bbx 32 per node)
    const size_t need_fast = (size_t)462848 * sizeof(float);  // ~1.85 MB

    if (ws_size >= need_fast) {
        float* agg  = ws;
        float* cnt  = ws + 131072;
        float* hs   = ws + 135168;
        float* hd   = ws + 167936;
        float* nrec = ws + 200704;

        // 256 compute blocks + 132 zeroing blocks (33792 float4 = agg+cnt)
        node_kernel<<<388, 256, 0, stream>>>(
            a, u, gpos, w1, b1, b2, hs, hd, nrec, agg);
        // 1024 blocks x 32 edges each
        edge_kernel<<<1024, 256, 0, stream>>>(
            ei, w2, hs, hd, nrec, agg, cnt);
        out_kernel<<<NB * 32 * 16 / 4, 256, 0, stream>>>(
            a, u, root, agg, cnt, out);
    } else {
        float* agg = ws;
        float* cnt = ws + NN * OUTC;
        hipMemsetAsync(d_ws, 0, (size_t)(NN * OUTC + NN) * sizeof(float), stream);
        edge_slow_kernel<<<EE / 256, 256, 0, stream>>>(
            a, u, gpos, ei, w1, b1, w2, b2, agg, cnt);
        out_fallback_kernel<<<(NB * NN) / 64, 64, 0, stream>>>(
            a, u, root, agg, cnt, out);
    }
}

// Round 4
// 98.820 us; speedup vs baseline: 1.1612x; 1.1612x over previous
//
#include <hip/hip_runtime.h>
#include <math.h>

// Problem constants (fixed by the reference)
#define NN   4096      // nodes per graph
#define EE   32768     // edges per graph (unique; B tiled copies are identical)
#define NB   4         // batch
#define ACc  16
#define UCc  16
#define INC  32        // AC+UC
#define OUTC 32
#define HID  8
#define EDGEC 68

__device__ __forceinline__ float gelu_exact(float v) {
    // jax.nn.gelu(approximate=False): x * 0.5 * (1 + erf(x/sqrt(2)))
    return 0.5f * v * (1.0f + erff(v * 0.70710678118654752f));
}

// ---------------------------------------------------------------------------
// Kernel 1: per-node precompute + workspace zeroing.
// Blocks [0,256): 16 nodes each.
//   nrec[n][0:32)  = x[n]            (transposed copy, contiguous per node)
//   nrec[n][32:64) = bbx[n][o] = sum_i x[n][i]*b2[i*32+o]
//   hs[n][k] = b1[k] + pw[n]·w1[k,0:34]; hd[n][k] = pw[n]·w1[k,34:68]
// Blocks [256,388): zero agg (131072 f) + cnt (4096 f) = 33792 float4.
// ---------------------------------------------------------------------------
__global__ __launch_bounds__(256) void node_kernel(
    const float* __restrict__ a, const float* __restrict__ u,
    const float* __restrict__ gpos,
    const float* __restrict__ w1, const float* __restrict__ b1,
    const float* __restrict__ b2,
    float* __restrict__ hs, float* __restrict__ hd,
    float* __restrict__ nrec, float* __restrict__ zbase)
{
    if (blockIdx.x >= 256) {
        int idx = (blockIdx.x - 256) * 256 + threadIdx.x;   // < 33792
        ((float4*)zbase)[idx] = make_float4(0.f, 0.f, 0.f, 0.f);
        return;
    }

    __shared__ float xs[16][36];       // [node][feature], 0..33 used
    __shared__ float w1s[HID * EDGEC]; // 544
    __shared__ float b2s[INC * OUTC];  // 1024
    __shared__ float b1s[HID];

    int tid = threadIdx.x;
    int n0 = blockIdx.x * 16;

    for (int i = tid; i < HID * EDGEC; i += 256) w1s[i] = w1[i];
    for (int i = tid; i < INC * OUTC; i += 256)  b2s[i] = b2[i];
    if (tid < HID) b1s[tid] = b1[tid];

    {   // stage x: 16 consecutive nodes per load group (coalesced 64B)
        int nn = tid & 15, cb = tid >> 4;
        #pragma unroll
        for (int j = 0; j < 2; ++j) {
            int c = cb + 16 * j;
            xs[nn][c] = (c < ACc) ? a[c * NN + n0 + nn]
                                  : u[(c - ACc) * NN + n0 + nn];
        }
    }
    if (tid < 32) {
        int nn = tid >> 1, dc = tid & 1;
        xs[nn][32 + dc] = gpos[(n0 + nn) * 2 + dc];
    }
    __syncthreads();

    // ---- xt + bbx: tid -> (o = tid&31, node slot = tid>>5, 2 nodes/thread)
    {
        int o = tid & 31, ns = tid >> 5;
        #pragma unroll
        for (int j = 0; j < 2; ++j) {
            int n = ns + 8 * j;
            float acc = 0.f;
            #pragma unroll
            for (int i = 0; i < INC; ++i) acc += xs[n][i] * b2s[i * OUTC + o];
            float* np = nrec + (size_t)(n0 + n) * 64;
            np[o]      = xs[n][o];
            np[32 + o] = acc;
        }
    }

    // ---- hs/hd: tid -> (n = tid>>4, idx = tid&15), one output each ----
    {
        int idx = tid & 15, n = tid >> 4;
        int k = idx & 7;
        bool dh = (idx >= 8);
        int base = k * EDGEC + (dh ? 34 : 0);
        float acc = dh ? 0.f : b1s[k];
        #pragma unroll
        for (int c = 0; c < 34; ++c) acc += xs[n][c] * w1s[base + c];
        (dh ? hd : hs)[(n0 + n) * HID + k] = acc;
    }
}

// ---------------------------------------------------------------------------
// Kernel 2: edge-parallel message + atomic scatter, NO G tensor.
// Block = 32 edges. Two phases:
//  Phase 1 (fully parallel staging): thread t = (e = t>>3, q = t&7)
//    xe[e][:] = x[s]  (float4 gather, 8 threads/edge, 128B coalesced)
//    be[e][:] = bbx[s]
//    ge[e][q] = gelu(hs[s][q] + hd[d][q])   <- gelu computed ONCE per (e,k)
//  Phase 2: thread t = (o = t>>3, k = t&7) holds w2[:,o,k] in 32 VGPRs
//    (w2[(i*32+o)*8+k] == w2[i*256+tid] -> one coalesced load per block).
//    For each of 32 edges: g = x·w2col (LDS broadcast reads, conflict-free),
//    m = ge[e][k]*g, 3x shfl_xor octet reduce, k==0 adds bbx and atomics.
// No serial dependent-load chain: all gathers issue in phase 1 in parallel.
// ---------------------------------------------------------------------------
__global__ __launch_bounds__(256) void edge_kernel(
    const int* __restrict__ ei, const float* __restrict__ w2,
    const float* __restrict__ hs, const float* __restrict__ hd,
    const float* __restrict__ nrec,
    float* __restrict__ agg, float* __restrict__ cnt)
{
    __shared__ float xe[32][32];   // 4 KB: x[s] per edge
    __shared__ float be[32][32];   // 4 KB: bbx[s] per edge
    __shared__ float ge[32][8];    // 1 KB: gelu(hs+hd) per edge
    __shared__ int   des[32];      // dest per edge

    int tid = threadIdx.x;
    int e0 = blockIdx.x * 32;

    // w2 column -> 32 VGPRs (coalesced; consumed in phase 2)
    float w2r[INC];
    #pragma unroll
    for (int i = 0; i < INC; ++i) w2r[i] = w2[i * 256 + tid];

    // ---- phase 1: parallel staging ----
    {
        int e = tid >> 3, q = tid & 7;
        int s = ei[e0 + e];
        int d = ei[EE + e0 + e];
        const float4* xp = (const float4*)(nrec + (size_t)s * 64);
        float4 xv = xp[q];
        float4 bv = xp[8 + q];
        float hv = gelu_exact(hs[s * HID + q] + hd[d * HID + q]);
        ((float4*)&xe[e][0])[q] = xv;
        ((float4*)&be[e][0])[q] = bv;
        ge[e][q] = hv;
        if (q == 0) des[e] = d;
    }
    __syncthreads();

    // edge-count atomics (1 per edge) issued early, off the critical path
    if (tid < 32) atomicAdd(&cnt[des[tid]], 1.0f);

    int k = tid & 7;
    int o = tid >> 3;          // 0..31

    // ---- phase 2: compute + scatter ----
    #pragma unroll 2
    for (int e = 0; e < 32; ++e) {
        const float4* xp = (const float4*)&xe[e][0];   // wave-uniform broadcast
        float4 x0 = xp[0], x1 = xp[1], x2 = xp[2], x3 = xp[3];
        float4 x4 = xp[4], x5 = xp[5], x6 = xp[6], x7 = xp[7];

        // 4 partial accumulators for ILP in the 32-FMA dot
        float g0 = x0.x*w2r[0]  + x0.y*w2r[1]  + x0.z*w2r[2]  + x0.w*w2r[3]
                 + x1.x*w2r[4]  + x1.y*w2r[5]  + x1.z*w2r[6]  + x1.w*w2r[7];
        float g1 = x2.x*w2r[8]  + x2.y*w2r[9]  + x2.z*w2r[10] + x2.w*w2r[11]
                 + x3.x*w2r[12] + x3.y*w2r[13] + x3.z*w2r[14] + x3.w*w2r[15];
        float g2 = x4.x*w2r[16] + x4.y*w2r[17] + x4.z*w2r[18] + x4.w*w2r[19]
                 + x5.x*w2r[20] + x5.y*w2r[21] + x5.z*w2r[22] + x5.w*w2r[23];
        float g3 = x6.x*w2r[24] + x6.y*w2r[25] + x6.z*w2r[26] + x6.w*w2r[27]
                 + x7.x*w2r[28] + x7.y*w2r[29] + x7.z*w2r[30] + x7.w*w2r[31];
        float g = (g0 + g1) + (g2 + g3);

        float m = ge[e][k] * g;
        m += __shfl_xor(m, 1, 64);
        m += __shfl_xor(m, 2, 64);
        m += __shfl_xor(m, 4, 64);

        if (k == 0) {
            m += be[e][o];
            atomicAdd(&agg[des[e] * OUTC + o], m);
        }
    }
}

// ---------------------------------------------------------------------------
// Kernel 3: output. agg holds SUM; divide by cnt here.
//   out[b,o,n] = (b==0 ? agg[n,o]/max(cnt,1) : 0) + sum_i x[b,n,i]*root[i,o]
// ---------------------------------------------------------------------------
__global__ __launch_bounds__(256) void out_kernel(
    const float* __restrict__ a, const float* __restrict__ u,
    const float* __restrict__ root, const float* __restrict__ agg,
    const float* __restrict__ cnt, float* __restrict__ out)
{
    __shared__ float rs[INC * OUTC];
    for (int i = threadIdx.x; i < INC * OUTC; i += 256) rs[i] = root[i];
    __syncthreads();

    int b     = blockIdx.x >> 7;          // 4
    int rem   = blockIdx.x & 127;
    int oq    = rem >> 4;                 // 8 o-quads
    int chunk = rem & 15;                 // 16 n-chunks
    int n = chunk * 256 + threadIdx.x;

    float x[INC];
    #pragma unroll
    for (int c = 0; c < ACc; ++c) x[c] = a[(b * ACc + c) * NN + n];
    #pragma unroll
    for (int c = 0; c < UCc; ++c) x[ACc + c] = u[(b * UCc + c) * NN + n];

    bool first = (b == 0);
    float inv = first ? 1.0f / fmaxf(cnt[n], 1.0f) : 0.0f;

    #pragma unroll
    for (int q = 0; q < 4; ++q) {
        int o = oq * 4 + q;
        float v = first ? agg[n * OUTC + o] * inv : 0.0f;
        #pragma unroll
        for (int i = 0; i < INC; ++i) v += x[i] * rs[i * OUTC + o];
        out[(b * OUTC + o) * NN + n] = v;
    }
}

// ---------------------------------------------------------------------------
// Fallback kernels (workspace too small): R0 slow path.
// ---------------------------------------------------------------------------
__global__ __launch_bounds__(256) void edge_slow_kernel(
    const float* __restrict__ a, const float* __restrict__ u,
    const float* __restrict__ gpos, const int* __restrict__ ei,
    const float* __restrict__ w1, const float* __restrict__ b1,
    const float* __restrict__ w2, const float* __restrict__ b2,
    float* __restrict__ agg, float* __restrict__ cnt)
{
    __shared__ float w1s[HID * EDGEC];
    __shared__ float b1s[HID];
    __shared__ float w2s[INC * OUTC * HID];
    __shared__ float b2s[INC * OUTC];
    for (int i = threadIdx.x; i < HID * EDGEC; i += 256)      w1s[i] = w1[i];
    for (int i = threadIdx.x; i < INC * OUTC * HID; i += 256) w2s[i] = w2[i];
    for (int i = threadIdx.x; i < INC * OUTC; i += 256)       b2s[i] = b2[i];
    if (threadIdx.x < HID) b1s[threadIdx.x] = b1[threadIdx.x];
    __syncthreads();

    int e = blockIdx.x * 256 + threadIdx.x;
    if (e >= EE) return;
    int s = ei[e];
    int d = ei[EE + e];

    float h[HID];
    #pragma unroll
    for (int k = 0; k < HID; ++k) h[k] = b1s[k];
    float xs[INC];

    #pragma unroll
    for (int c = 0; c < ACc; ++c) {
        float v = a[c * NN + s]; xs[c] = v;
        #pragma unroll
        for (int k = 0; k < HID; ++k) h[k] += v * w1s[k * EDGEC + c];
    }
    #pragma unroll
    for (int c = 0; c < UCc; ++c) {
        float v = u[c * NN + s]; xs[ACc + c] = v;
        #pragma unroll
        for (int k = 0; k < HID; ++k) h[k] += v * w1s[k * EDGEC + ACc + c];
    }
    {
        float v0 = gpos[s * 2], v1 = gpos[s * 2 + 1];
        #pragma unroll
        for (int k = 0; k < HID; ++k)
            h[k] += v0 * w1s[k * EDGEC + 32] + v1 * w1s[k * EDGEC + 33];
    }
    #pragma unroll
    for (int c = 0; c < ACc; ++c) {
        float v = a[c * NN + d];
        #pragma unroll
        for (int k = 0; k < HID; ++k) h[k] += v * w1s[k * EDGEC + 34 + c];
    }
    #pragma unroll
    for (int c = 0; c < UCc; ++c) {
        float v = u[c * NN + d];
        #pragma unroll
        for (int k = 0; k < HID; ++k) h[k] += v * w1s[k * EDGEC + 50 + c];
    }
    {
        float v0 = gpos[d * 2], v1 = gpos[d * 2 + 1];
        #pragma unroll
        for (int k = 0; k < HID; ++k)
            h[k] += v0 * w1s[k * EDGEC + 66] + v1 * w1s[k * EDGEC + 67];
    }
    #pragma unroll
    for (int k = 0; k < HID; ++k) h[k] = gelu_exact(h[k]);

    float* aggd = agg + d * OUTC;
    for (int o = 0; o < OUTC; ++o) {
        float m = 0.0f;
        #pragma unroll 4
        for (int i = 0; i < INC; ++i) {
            int r = i * OUTC + o;
            float wv = b2s[r];
            const float* wp = &w2s[r * HID];
            #pragma unroll
            for (int k = 0; k < HID; ++k) wv += h[k] * wp[k];
            m += xs[i] * wv;
        }
        atomicAdd(aggd + o, m);
    }
    atomicAdd(cnt + d, 1.0f);
}

__global__ __launch_bounds__(64) void out_fallback_kernel(
    const float* __restrict__ a, const float* __restrict__ u,
    const float* __restrict__ root,
    const float* __restrict__ agg, const float* __restrict__ cnt,
    float* __restrict__ out)
{
    __shared__ float rs[INC * OUTC];
    for (int i = threadIdx.x; i < INC * OUTC; i += 64) rs[i] = root[i];
    __syncthreads();

    int idx = blockIdx.x * 64 + threadIdx.x;
    int b = idx >> 12;
    int n = idx & (NN - 1);

    float x[INC];
    #pragma unroll
    for (int c = 0; c < ACc; ++c) x[c] = a[(b * ACc + c) * NN + n];
    #pragma unroll
    for (int c = 0; c < UCc; ++c) x[ACc + c] = u[(b * UCc + c) * NN + n];

    bool first = (b == 0);
    float inv = 0.0f;
    if (first) inv = 1.0f / fmaxf(cnt[n], 1.0f);

    for (int o = 0; o < OUTC; ++o) {
        float v = first ? agg[n * OUTC + o] * inv : 0.0f;
        #pragma unroll
        for (int i = 0; i < INC; ++i) v += x[i] * rs[i * OUTC + o];
        out[(b * OUTC + o) * NN + n] = v;
    }
}

extern "C" void kernel_launch(void* const* d_in, const int* in_sizes, int n_in,
                              void* d_out, int out_size, void* d_ws, size_t ws_size,
                              hipStream_t stream) {
    const float* a    = (const float*)d_in[0];
    const float* u    = (const float*)d_in[1];
    const float* gpos = (const float*)d_in[2];
    const int*   ei   = (const int*)d_in[3];
    const float* w1   = (const float*)d_in[4];
    const float* b1   = (const float*)d_in[5];
    const float* w2   = (const float*)d_in[6];
    const float* b2   = (const float*)d_in[7];
    const float* root = (const float*)d_in[8];
    float* out = (float*)d_out;

    float* ws = (float*)d_ws;

    // fast-path workspace layout (floats):
    //   agg  [0,       +131072)
    //   cnt  [131072,  +4096)     (agg..cnt zeroed by node_kernel tail blocks)
    //   hs   [135168,  +32768)
    //   hd   [167936,  +32768)
    //   nrec [200704,  +262144)   (xt 32 + bbx 32 per node)
    const size_t need_fast = (size_t)462848 * sizeof(float);  // ~1.85 MB

    if (ws_size >= need_fast) {
        float* agg  = ws;
        float* cnt  = ws + 131072;
        float* hs   = ws + 135168;
        float* hd   = ws + 167936;
        float* nrec = ws + 200704;

        // 256 compute blocks + 132 zeroing blocks (33792 float4 = agg+cnt)
        node_kernel<<<388, 256, 0, stream>>>(
            a, u, gpos, w1, b1, b2, hs, hd, nrec, agg);
        // 1024 blocks x 32 edges each (two-phase, parallel staging)
        edge_kernel<<<1024, 256, 0, stream>>>(
            ei, w2, hs, hd, nrec, agg, cnt);
        out_kernel<<<NB * 32 * 16 / 4, 256, 0, stream>>>(
            a, u, root, agg, cnt, out);
    } else {
        float* agg = ws;
        float* cnt = ws + NN * OUTC;
        hipMemsetAsync(d_ws, 0, (size_t)(NN * OUTC + NN) * sizeof(float), stream);
        edge_slow_kernel<<<EE / 256, 256, 0, stream>>>(
            a, u, gpos, ei, w1, b1, w2, b2, agg, cnt);
        out_fallback_kernel<<<(NB * NN) / 64, 64, 0, stream>>>(
            a, u, root, agg, cnt, out);
    }
}

// Round 5
// 92.617 us; speedup vs baseline: 1.2390x; 1.0670x over previous
//
#include <hip/hip_runtime.h>
#include <math.h>

// Problem constants (fixed by the reference)
#define NN   4096      // nodes per graph
#define EE   32768     // edges per graph (unique; B tiled copies are identical)
#define NB   4         // batch
#define ACc  16
#define UCc  16
#define INC  32        // AC+UC
#define OUTC 32
#define HID  8
#define EDGEC 68

__device__ __forceinline__ float gelu_exact(float v) {
    // jax.nn.gelu(approximate=False): x * 0.5 * (1 + erf(x/sqrt(2)))
    return 0.5f * v * (1.0f + erff(v * 0.70710678118654752f));
}

// ---------------------------------------------------------------------------
// Kernel 1: per-node precompute + workspace zeroing. (R1-proven structure)
// Blocks [0,512): 8 nodes each; thread = (o,k) column owner of w2.
//   rec[n][o*8+k] = G[n][o][k] = sum_i x[n][i]*w2[(i*32+o)*8+k]
//   rec[n][256+o] = bbx[n][o]  = sum_i x[n][i]*b2[i*32+o]
//   hs[n][k] = b1[k] + pw[n]·w1[k,0:34]; hd[n][k] = pw[n]·w1[k,34:68]
// Blocks [512,644): zero agg (131072 f) + cnt (4096 f) = 33792 float4.
// ---------------------------------------------------------------------------
__global__ __launch_bounds__(256) void node_kernel(
    const float* __restrict__ a, const float* __restrict__ u,
    const float* __restrict__ gpos,
    const float* __restrict__ w1, const float* __restrict__ b1,
    const float* __restrict__ w2, const float* __restrict__ b2,
    float* __restrict__ hs, float* __restrict__ hd,
    float* __restrict__ rec, float* __restrict__ zbase)
{
    if (blockIdx.x >= 512) {
        int idx = (blockIdx.x - 512) * 256 + threadIdx.x;   // < 33792
        ((float4*)zbase)[idx] = make_float4(0.f, 0.f, 0.f, 0.f);
        return;
    }

    __shared__ float xs[8][36];        // [node][feature], 0..33 used
    __shared__ float w1s[HID * EDGEC]; // 544
    __shared__ float b2s[INC * OUTC];  // 1024
    __shared__ float b1s[HID];

    int tid = threadIdx.x;
    int n0 = blockIdx.x * 8;

    for (int i = tid; i < HID * EDGEC; i += 256) w1s[i] = w1[i];
    for (int i = tid; i < INC * OUTC; i += 256)  b2s[i] = b2[i];
    if (tid < HID) b1s[tid] = b1[tid];

    {   // stage x: tid = c*8 + nn
        int c = tid >> 3, nn = tid & 7;
        float v = (c < ACc) ? a[c * NN + n0 + nn]
                            : u[(c - ACc) * NN + n0 + nn];
        xs[nn][c] = v;
        if (tid < 16) {
            int nn2 = tid >> 1, dce = tid & 1;
            xs[nn2][32 + dce] = gpos[(n0 + nn2) * 2 + dce];
        }
    }

    // w2 column into registers (independent of LDS, issued before sync)
    float w2r[INC];
    #pragma unroll
    for (int i = 0; i < INC; ++i) w2r[i] = w2[i * 256 + tid];

    __syncthreads();

    // ---- G phase: one output float per node per thread ----
    #pragma unroll
    for (int n = 0; n < 8; ++n) {
        const float4* xp = (const float4*)xs[n];   // 144B rows -> 16B aligned
        float4 x0 = xp[0], x1 = xp[1], x2 = xp[2], x3 = xp[3];
        float4 x4 = xp[4], x5 = xp[5], x6 = xp[6], x7 = xp[7];
        float acc = 0.f;
        acc += x0.x*w2r[0]  + x0.y*w2r[1]  + x0.z*w2r[2]  + x0.w*w2r[3];
        acc += x1.x*w2r[4]  + x1.y*w2r[5]  + x1.z*w2r[6]  + x1.w*w2r[7];
        acc += x2.x*w2r[8]  + x2.y*w2r[9]  + x2.z*w2r[10] + x2.w*w2r[11];
        acc += x3.x*w2r[12] + x3.y*w2r[13] + x3.z*w2r[14] + x3.w*w2r[15];
        acc += x4.x*w2r[16] + x4.y*w2r[17] + x4.z*w2r[18] + x4.w*w2r[19];
        acc += x5.x*w2r[20] + x5.y*w2r[21] + x5.z*w2r[22] + x5.w*w2r[23];
        acc += x6.x*w2r[24] + x6.y*w2r[25] + x6.z*w2r[26] + x6.w*w2r[27];
        acc += x7.x*w2r[28] + x7.y*w2r[29] + x7.z*w2r[30] + x7.w*w2r[31];
        rec[(size_t)(n0 + n) * 288 + tid] = acc;
    }

    // ---- bbx phase: tid -> (n = tid>>5, o = tid&31) ----
    {
        int n = tid >> 5, o = tid & 31;
        float acc = 0.f;
        #pragma unroll
        for (int i = 0; i < INC; ++i) acc += xs[n][i] * b2s[i * OUTC + o];
        rec[(size_t)(n0 + n) * 288 + 256 + o] = acc;
    }

    // ---- hs/hd phase: threads 0..127 -> (n = t>>4, idx = t&15) ----
    if (tid < 128) {
        int n = tid >> 4, idx = tid & 15;
        int k = idx & 7;
        bool dsth = (idx >= 8);
        int base = k * EDGEC + (dsth ? 34 : 0);
        float hv = dsth ? 0.0f : b1s[k];
        #pragma unroll
        for (int c = 0; c < 34; ++c) hv += xs[n][c] * w1s[base + c];
        (dsth ? hd : hs)[(n0 + n) * HID + k] = hv;
    }
}

// ---------------------------------------------------------------------------
// Kernel 2 (R1-proven): fully edge-parallel message + atomic scatter.
// thread t -> (e = t>>5, o = t&31); 32 lanes per edge, 1M threads total.
//   h = gelu(hs[s]+hd[d]) on lanes o<8, broadcast via 8 shfl;
//   msg[o] = bbx[s][o] + sum_k h[k]*G[s][o][k]  (two float4 loads, 8 FMA)
//   atomicAdd agg[d][o] (32 lanes -> one 128B line); o==0 counts the edge.
// ---------------------------------------------------------------------------
__global__ __launch_bounds__(256) void edge_kernel(
    const int* __restrict__ ei,
    const float* __restrict__ hs, const float* __restrict__ hd,
    const float* __restrict__ rec,
    float* __restrict__ agg, float* __restrict__ cnt)
{
    int t = blockIdx.x * 256 + threadIdx.x;
    int e = t >> 5;                 // edge id, < EE
    int o = t & 31;

    int s = ei[e];
    int d = ei[EE + e];

    float hval = 0.f;
    if (o < HID) hval = gelu_exact(hs[s * HID + o] + hd[d * HID + o]);

    int sb = (threadIdx.x & 63) & 32;   // base lane of this 32-lane group
    float h0 = __shfl(hval, sb + 0, 64);
    float h1 = __shfl(hval, sb + 1, 64);
    float h2 = __shfl(hval, sb + 2, 64);
    float h3 = __shfl(hval, sb + 3, 64);
    float h4 = __shfl(hval, sb + 4, 64);
    float h5 = __shfl(hval, sb + 5, 64);
    float h6 = __shfl(hval, sb + 6, 64);
    float h7 = __shfl(hval, sb + 7, 64);

    const float* rp = rec + (size_t)s * 288;
    const float4* gp = (const float4*)(rp + o * HID);
    float4 g0 = gp[0], g1 = gp[1];
    float m = rp[256 + o]
            + h0 * g0.x + h1 * g0.y + h2 * g0.z + h3 * g0.w
            + h4 * g1.x + h5 * g1.y + h6 * g1.z + h7 * g1.w;

    atomicAdd(&agg[d * OUTC + o], m);
    if (o == 0) atomicAdd(&cnt[d], 1.0f);
}

// ---------------------------------------------------------------------------
// Kernel 3: output. agg holds SUM; divide by cnt here.
//   out[b,o,n] = (b==0 ? agg[n,o]/max(cnt,1) : 0) + sum_i x[b,n,i]*root[i,o]
// agg read as ONE float4 per thread (4 consecutive o) instead of 4 scalars.
// ---------------------------------------------------------------------------
__global__ __launch_bounds__(256) void out_kernel(
    const float* __restrict__ a, const float* __restrict__ u,
    const float* __restrict__ root, const float* __restrict__ agg,
    const float* __restrict__ cnt, float* __restrict__ out)
{
    __shared__ float rs[INC * OUTC];
    for (int i = threadIdx.x; i < INC * OUTC; i += 256) rs[i] = root[i];
    __syncthreads();

    int b     = blockIdx.x >> 7;          // 4
    int rem   = blockIdx.x & 127;
    int oq    = rem >> 4;                 // 8 o-quads
    int chunk = rem & 15;                 // 16 n-chunks
    int n = chunk * 256 + threadIdx.x;

    float x[INC];
    #pragma unroll
    for (int c = 0; c < ACc; ++c) x[c] = a[(b * ACc + c) * NN + n];
    #pragma unroll
    for (int c = 0; c < UCc; ++c) x[ACc + c] = u[(b * UCc + c) * NN + n];

    bool first = (b == 0);
    float inv = first ? 1.0f / fmaxf(cnt[n], 1.0f) : 0.0f;

    float4 ag = make_float4(0.f, 0.f, 0.f, 0.f);
    if (first) ag = *(const float4*)&agg[n * OUTC + oq * 4];
    float agv[4] = {ag.x * inv, ag.y * inv, ag.z * inv, ag.w * inv};

    #pragma unroll
    for (int q = 0; q < 4; ++q) {
        int o = oq * 4 + q;
        float v = agv[q];
        #pragma unroll
        for (int i = 0; i < INC; ++i) v += x[i] * rs[i * OUTC + o];
        out[(b * OUTC + o) * NN + n] = v;
    }
}

// ---------------------------------------------------------------------------
// Fallback kernels (workspace too small): R0 slow path.
// ---------------------------------------------------------------------------
__global__ __launch_bounds__(256) void edge_slow_kernel(
    const float* __restrict__ a, const float* __restrict__ u,
    const float* __restrict__ gpos, const int* __restrict__ ei,
    const float* __restrict__ w1, const float* __restrict__ b1,
    const float* __restrict__ w2, const float* __restrict__ b2,
    float* __restrict__ agg, float* __restrict__ cnt)
{
    __shared__ float w1s[HID * EDGEC];
    __shared__ float b1s[HID];
    __shared__ float w2s[INC * OUTC * HID];
    __shared__ float b2s[INC * OUTC];
    for (int i = threadIdx.x; i < HID * EDGEC; i += 256)      w1s[i] = w1[i];
    for (int i = threadIdx.x; i < INC * OUTC * HID; i += 256) w2s[i] = w2[i];
    for (int i = threadIdx.x; i < INC * OUTC; i += 256)       b2s[i] = b2[i];
    if (threadIdx.x < HID) b1s[threadIdx.x] = b1[threadIdx.x];
    __syncthreads();

    int e = blockIdx.x * 256 + threadIdx.x;
    if (e >= EE) return;
    int s = ei[e];
    int d = ei[EE + e];

    float h[HID];
    #pragma unroll
    for (int k = 0; k < HID; ++k) h[k] = b1s[k];
    float xs[INC];

    #pragma unroll
    for (int c = 0; c < ACc; ++c) {
        float v = a[c * NN + s]; xs[c] = v;
        #pragma unroll
        for (int k = 0; k < HID; ++k) h[k] += v * w1s[k * EDGEC + c];
    }
    #pragma unroll
    for (int c = 0; c < UCc; ++c) {
        float v = u[c * NN + s]; xs[ACc + c] = v;
        #pragma unroll
        for (int k = 0; k < HID; ++k) h[k] += v * w1s[k * EDGEC + ACc + c];
    }
    {
        float v0 = gpos[s * 2], v1 = gpos[s * 2 + 1];
        #pragma unroll
        for (int k = 0; k < HID; ++k)
            h[k] += v0 * w1s[k * EDGEC + 32] + v1 * w1s[k * EDGEC + 33];
    }
    #pragma unroll
    for (int c = 0; c < ACc; ++c) {
        float v = a[c * NN + d];
        #pragma unroll
        for (int k = 0; k < HID; ++k) h[k] += v * w1s[k * EDGEC + 34 + c];
    }
    #pragma unroll
    for (int c = 0; c < UCc; ++c) {
        float v = u[c * NN + d];
        #pragma unroll
        for (int k = 0; k < HID; ++k) h[k] += v * w1s[k * EDGEC + 50 + c];
    }
    {
        float v0 = gpos[d * 2], v1 = gpos[d * 2 + 1];
        #pragma unroll
        for (int k = 0; k < HID; ++k)
            h[k] += v0 * w1s[k * EDGEC + 66] + v1 * w1s[k * EDGEC + 67];
    }
    #pragma unroll
    for (int k = 0; k < HID; ++k) h[k] = gelu_exact(h[k]);

    float* aggd = agg + d * OUTC;
    for (int o = 0; o < OUTC; ++o) {
        float m = 0.0f;
        #pragma unroll 4
        for (int i = 0; i < INC; ++i) {
            int r = i * OUTC + o;
            float wv = b2s[r];
            const float* wp = &w2s[r * HID];
            #pragma unroll
            for (int k = 0; k < HID; ++k) wv += h[k] * wp[k];
            m += xs[i] * wv;
        }
        atomicAdd(aggd + o, m);
    }
    atomicAdd(cnt + d, 1.0f);
}

__global__ __launch_bounds__(64) void out_fallback_kernel(
    const float* __restrict__ a, const float* __restrict__ u,
    const float* __restrict__ root,
    const float* __restrict__ agg, const float* __restrict__ cnt,
    float* __restrict__ out)
{
    __shared__ float rs[INC * OUTC];
    for (int i = threadIdx.x; i < INC * OUTC; i += 64) rs[i] = root[i];
    __syncthreads();

    int idx = blockIdx.x * 64 + threadIdx.x;
    int b = idx >> 12;
    int n = idx & (NN - 1);

    float x[INC];
    #pragma unroll
    for (int c = 0; c < ACc; ++c) x[c] = a[(b * ACc + c) * NN + n];
    #pragma unroll
    for (int c = 0; c < UCc; ++c) x[ACc + c] = u[(b * UCc + c) * NN + n];

    bool first = (b == 0);
    float inv = 0.0f;
    if (first) inv = 1.0f / fmaxf(cnt[n], 1.0f);

    for (int o = 0; o < OUTC; ++o) {
        float v = first ? agg[n * OUTC + o] * inv : 0.0f;
        #pragma unroll
        for (int i = 0; i < INC; ++i) v += x[i] * rs[i * OUTC + o];
        out[(b * OUTC + o) * NN + n] = v;
    }
}

extern "C" void kernel_launch(void* const* d_in, const int* in_sizes, int n_in,
                              void* d_out, int out_size, void* d_ws, size_t ws_size,
                              hipStream_t stream) {
    const float* a    = (const float*)d_in[0];
    const float* u    = (const float*)d_in[1];
    const float* gpos = (const float*)d_in[2];
    const int*   ei   = (const int*)d_in[3];
    const float* w1   = (const float*)d_in[4];
    const float* b1   = (const float*)d_in[5];
    const float* w2   = (const float*)d_in[6];
    const float* b2   = (const float*)d_in[7];
    const float* root = (const float*)d_in[8];
    float* out = (float*)d_out;

    float* ws = (float*)d_ws;

    // fast-path workspace layout (floats):
    //   agg [0,       +131072)
    //   cnt [131072,  +4096)     (agg..cnt zeroed by node_kernel tail blocks)
    //   hs  [135168,  +32768)
    //   hd  [167936,  +32768)
    //   rec [200704,  +1179648)  (G 256 + bbx 32 per node, 288 floats)
    const size_t need_fast = (size_t)1380352 * sizeof(float);  // ~5.52 MB

    if (ws_size >= need_fast) {
        float* agg = ws;
        float* cnt = ws + 131072;
        float* hs  = ws + 135168;
        float* hd  = ws + 167936;
        float* rec = ws + 200704;

        // 512 compute blocks + 132 zeroing blocks (33792 float4 = agg+cnt)
        node_kernel<<<644, 256, 0, stream>>>(
            a, u, gpos, w1, b1, w2, b2, hs, hd, rec, agg);
        // fully edge-parallel: EE*32 threads
        edge_kernel<<<EE * 32 / 256, 256, 0, stream>>>(
            ei, hs, hd, rec, agg, cnt);
        out_kernel<<<NB * 32 * 16 / 4, 256, 0, stream>>>(
            a, u, root, agg, cnt, out);
    } else {
        float* agg = ws;
        float* cnt = ws + NN * OUTC;
        hipMemsetAsync(d_ws, 0, (size_t)(NN * OUTC + NN) * sizeof(float), stream);
        edge_slow_kernel<<<EE / 256, 256, 0, stream>>>(
            a, u, gpos, ei, w1, b1, w2, b2, agg, cnt);
        out_fallback_kernel<<<(NB * NN) / 64, 64, 0, stream>>>(
            a, u, root, agg, cnt, out);
    }
}